// Round 6
// baseline (5029.816 us; speedup 1.0000x reference)
//
#include <hip/hip_runtime.h>
#include <hip/hip_bf16.h>

// SimpleBiGRU on MI355X — R5: dual-region publish + adaptive poll.
// Both "directions" are forward-in-time GRU scans (batch-flip is identity).
// 8 units = (dir) x (batch-group of 16 rows); 32 WGs (1 wave each) per unit
// (unit = wg%8 -> co-XCD under round-robin dispatch), each owning 16 hidden
// columns x 3 gates.
//
// h broadcast: u32 = (bf16 << 16) | tag, tag = step+1. Producer stores the
// tagged fragments to BOTH a local region (plain/workgroup-scope store ->
// lands in its XCD's L2) and an LLC region (agent-scope store, R4b path).
// Consumer polls the local region with sc0 (L2-coherent) loads; if the
// producer is not co-XCD the local line goes stale-forever, so after 4
// failed tries the poll alternates with sc0+sc1 (LLC) reads of the second
// region — always correct, any WG->XCD mapping (tag==t <=> step-t data).
//
// MFMA convention (swapped, layout-safe k-slot mapping k = ks*32 + lg*8 + j):
//   acc = MFMA(W_frag, act_frag, acc); D: row = 4*lg+reg = out-col offset,
//   col = l15 = batch row. Lane owns 4 adjacent h-cols of one batch row.

#define TT 512
#define FF 256
#define HH 512
#define G3 1536
#define NWG 256
#define NTHR 64

typedef __attribute__((ext_vector_type(8))) short short8;   // 8 x bf16
typedef __attribute__((ext_vector_type(4))) float f32x4;
typedef unsigned int u32;
typedef unsigned long long u64;

union U4 { uint4 v; u32 u[4]; u64 q[2]; };

__device__ __forceinline__ unsigned short f2bf(float f) {
  union { float f; unsigned u; } x; x.f = f;
  return (unsigned short)((x.u + 0x7fffu + ((x.u >> 16) & 1u)) >> 16);  // RNE
}

__device__ __forceinline__ unsigned pk2(float a, float b) {
  union { __hip_bfloat162 h; unsigned u; } x;
  x.h = __float22bfloat162_rn(make_float2(a, b));
  return x.u;  // low 16 = a, high 16 = b
}

__device__ __forceinline__ float sigm(float x) {
  return __builtin_amdgcn_rcpf(1.f + __expf(-x));
}

#define MFMA(a, b, c) __builtin_amdgcn_mfma_f32_16x16x32_bf16((a), (b), (c), 0, 0, 0)

__global__ __launch_bounds__(NTHR, 1) void gru_fused(
    const float* __restrict__ data,
    const float* __restrict__ Wi_f, const float* __restrict__ bi_f,
    const float* __restrict__ Wh_f, const float* __restrict__ bhn_f,
    const float* __restrict__ Wi_b, const float* __restrict__ bi_b,
    const float* __restrict__ Wh_b, const float* __restrict__ bhn_b,
    float* __restrict__ out,
    u32* __restrict__ hbufL,   // local region  [unit][buf][row16][col512]
    u32* __restrict__ hbufG)   // LLC region    [unit][buf][row16][col512]
{
  const int wg   = blockIdx.x;
  const int unit = wg & 7;      // co-XCD under round-robin dispatch
  const int s    = wg >> 3;     // column slice 0..31
  const int dir  = unit >> 2;
  const int bg   = unit & 3;
  const int lane = threadIdx.x; // 0..63
  const int l15  = lane & 15;
  const int lg   = lane >> 4;

  const float* Wi  = dir ? Wi_b  : Wi_f;
  const float* Wh  = dir ? Wh_b  : Wh_f;
  const float* bi  = dir ? bi_b  : bi_f;
  const float* bhn = dir ? bhn_b : bhn_f;

  const int colT = s * 16 + l15;        // weight-fragment column (A m-index)
  const int colBase = s * 16 + lg * 4;  // this lane's 4 output columns

  // ---- one-time: weight A-fragments into registers (k = ks*32+lg*8+j) ----
  short8 whf[3][16];
#pragma unroll
  for (int g = 0; g < 3; ++g)
#pragma unroll
    for (int ks = 0; ks < 16; ++ks) {
      short8 v;
#pragma unroll
      for (int j = 0; j < 8; ++j)
        v[j] = (short)f2bf(Wh[(size_t)(ks * 32 + lg * 8 + j) * G3 + g * HH + colT]);
      whf[g][ks] = v;
    }
  short8 wif[3][8];
#pragma unroll
  for (int g = 0; g < 3; ++g)
#pragma unroll
    for (int ks = 0; ks < 8; ++ks) {
      short8 v;
#pragma unroll
      for (int j = 0; j < 8; ++j)
        v[j] = (short)f2bf(Wi[(size_t)(ks * 32 + lg * 8 + j) * G3 + g * HH + colT]);
      wif[g][ks] = v;
    }
  float biR[4], biZ[4], biN[4], bhc[4];
#pragma unroll
  for (int j = 0; j < 4; ++j) {
    biR[j] = bi[colBase + j];
    biZ[j] = bi[HH + colBase + j];
    biN[j] = bi[2 * HH + colBase + j];
    bhc[j] = bhn[colBase + j];
  }

  const float* xbase = data + (size_t)(bg * 16 + l15) * TT * FF;
  float hp[4] = {0.f, 0.f, 0.f, 0.f};  // fp32 carry: batch l15, cols colBase+j

  for (int t = 0; t < TT; ++t) {
    // ---- xg phase (h-independent; issues before the poll) ----
    f32x4 accR = {0.f, 0.f, 0.f, 0.f};
    f32x4 accZ = {0.f, 0.f, 0.f, 0.f};
    f32x4 xN   = {0.f, 0.f, 0.f, 0.f};
    {
      const float* xr = xbase + (size_t)t * FF;
#pragma unroll
      for (int ks = 0; ks < 8; ++ks) {
        float4 x0 = *(const float4*)(xr + ks * 32 + lg * 8);
        float4 x1 = *(const float4*)(xr + ks * 32 + lg * 8 + 4);
        union { short8 s; unsigned u[4]; } a;
        a.u[0] = pk2(x0.x, x0.y); a.u[1] = pk2(x0.z, x0.w);
        a.u[2] = pk2(x1.x, x1.y); a.u[3] = pk2(x1.z, x1.w);
        accR = MFMA(wif[0][ks], a.s, accR);
        accZ = MFMA(wif[1][ks], a.s, accZ);
        xN   = MFMA(wif[2][ks], a.s, xN);
      }
    }

    // ---- adaptive tagged poll ----
    const u32 tag = (u32)t;
    const size_t boff = (size_t)(unit * 2 + (t & 1)) << 13;  // 16*512 u32
    const u32* hbL = hbufL + boff;
    const u32* hbG = hbufG + boff;
    U4 q[32];
    int it = 0;
    while (true) {
      const bool llc = (it >= 4) && (it & 1);
      if (llc) {
#pragma unroll
        for (int ks = 0; ks < 16; ++ks) {
          const u32* p = hbG + l15 * 512 + ks * 32 + lg * 8;
          asm volatile("global_load_dwordx4 %0, %1, off sc0 sc1"
                       : "=v"(q[2 * ks].v) : "v"(p));
          asm volatile("global_load_dwordx4 %0, %1, off sc0 sc1"
                       : "=v"(q[2 * ks + 1].v) : "v"(p + 4));
        }
      } else {
#pragma unroll
        for (int ks = 0; ks < 16; ++ks) {
          const u32* p = hbL + l15 * 512 + ks * 32 + lg * 8;
          asm volatile("global_load_dwordx4 %0, %1, off sc0"
                       : "=v"(q[2 * ks].v) : "v"(p));
          asm volatile("global_load_dwordx4 %0, %1, off sc0"
                       : "=v"(q[2 * ks + 1].v) : "v"(p + 4));
        }
      }
      asm volatile("s_waitcnt vmcnt(0)" ::: "memory");
      u32 bad = 0;
#pragma unroll
      for (int c = 0; c < 32; ++c) {
        bad |= (q[c].u[0] ^ tag) & 0xffffu;   // tag of 8B granule {w0,w1}
        bad |= (q[c].u[3] ^ tag) & 0xffffu;   // tag of 8B granule {w2,w3}
      }
      if (__all(bad == 0)) break;
      ++it;
    }

    // ---- pack B-fragments (strip tags) + hg MFMAs ----
    f32x4 hN = {0.f, 0.f, 0.f, 0.f};
#pragma unroll
    for (int ks = 0; ks < 16; ++ks) {
      union { short8 s; unsigned u[4]; } a;
#pragma unroll
      for (int i = 0; i < 2; ++i) {
        const U4& c = q[2 * ks + i];
        a.u[2 * i]     = __builtin_amdgcn_perm(c.u[1], c.u[0], 0x07060302u);
        a.u[2 * i + 1] = __builtin_amdgcn_perm(c.u[3], c.u[2], 0x07060302u);
      }
      accR = MFMA(whf[0][ks], a.s, accR);
      accZ = MFMA(whf[1][ks], a.s, accZ);
      hN   = MFMA(whf[2][ks], a.s, hN);
    }

    // ---- gates: lane holds (batch=l15, cols=colBase..+3) ----
    float hv[4];
#pragma unroll
    for (int j = 0; j < 4; ++j) {
      float r = sigm(accR[j] + biR[j]);
      float z = sigm(accZ[j] + biZ[j]);
      float e = __expf(2.f * (xN[j] + biN[j] + r * (hN[j] + bhc[j])));
      float n = 1.f - 2.f * __builtin_amdgcn_rcpf(e + 1.f);  // tanh
      hv[j] = (1.f - z) * n + z * hp[j];
      hp[j] = hv[j];
    }

    // ---- publish: tagged 8B stores to local (L2) then LLC region ----
    {
      U4 w;
      const u32 wtag = (u32)(t + 1);
#pragma unroll
      for (int j = 0; j < 4; ++j)
        w.u[j] = ((u32)f2bf(hv[j]) << 16) | wtag;
      const size_t ooff = ((size_t)(unit * 2 + ((t + 1) & 1)) << 13)
                        + l15 * 512 + s * 16 + lg * 4;
      u64* pL = (u64*)(hbufL + ooff);
      u64* pG = (u64*)(hbufG + ooff);
      __hip_atomic_store(&pL[0], w.q[0], __ATOMIC_RELAXED, __HIP_MEMORY_SCOPE_WORKGROUP);
      __hip_atomic_store(&pL[1], w.q[1], __ATOMIC_RELAXED, __HIP_MEMORY_SCOPE_WORKGROUP);
      __hip_atomic_store(&pG[0], w.q[0], __ATOMIC_RELAXED, __HIP_MEMORY_SCOPE_AGENT);
      __hip_atomic_store(&pG[1], w.q[1], __ATOMIC_RELAXED, __HIP_MEMORY_SCOPE_AGENT);
    }

    // ---- out store (off critical path): one float4 per lane ----
    *(float4*)(out + ((size_t)(bg * 16 + l15) * TT + t) * 1024 + (size_t)dir * HH + colBase)
        = make_float4(hv[0], hv[1], hv[2], hv[3]);
  }
}

extern "C" void kernel_launch(void* const* d_in, const int* in_sizes, int n_in,
                              void* d_out, int out_size, void* d_ws, size_t ws_size,
                              hipStream_t stream) {
  const float* data  = (const float*)d_in[0];
  const float* Wi_f  = (const float*)d_in[1];
  const float* bi_f  = (const float*)d_in[2];
  const float* Wh_f  = (const float*)d_in[3];
  const float* bhn_f = (const float*)d_in[4];
  const float* Wi_b  = (const float*)d_in[5];
  const float* bi_b  = (const float*)d_in[6];
  const float* Wh_b  = (const float*)d_in[7];
  const float* bhn_b = (const float*)d_in[8];
  float* out = (float*)d_out;

  // ws: [0, 512KB) local tagged h buffers; [512KB, 1MB) LLC tagged h buffers.
  // memset(0) == valid tag-0 zero state => uniform t=0 path.
  u32* hbufL = (u32*)d_ws;
  u32* hbufG = (u32*)((char*)d_ws + 524288);
  (void)hipMemsetAsync(d_ws, 0, 1048576, stream);

  gru_fused<<<NWG, NTHR, 0, stream>>>(data, Wi_f, bi_f, Wh_f, bhn_f,
                                      Wi_b, bi_b, Wh_b, bhn_b, out, hbufL, hbufG);
}

// Round 7
// 3756.357 us; speedup vs baseline: 1.3390x; 1.3390x over previous
//
#include <hip/hip_runtime.h>
#include <hip/hip_bf16.h>

// SimpleBiGRU on MI355X — R6: R4b worker + heater waves to pin SCLK.
// Both "directions" are forward-in-time GRU scans (batch-flip is identity).
// 8 units = (dir) x (batch-group of 16 rows); 32 WGs per unit; in each WG,
// wave 0 is the worker (identical to R4b: tagged-data poll, no flags, no
// drain), waves 1-3 are DVFS heaters: register-only FMA spin until the
// worker raises an LDS done flag. Heaters occupy the CU's other SIMDs, so
// they never contend with the worker's issue slots, but keep chip
// utilization (and thus SCLK) high — attacking the ~6x wall-clock inflation
// of every coherence RTT seen in R3/R4b (97%-idle GPU => idle-floor clocks).
//
// h broadcast: u32 = (bf16 << 16) | tag, tag = step+1. Consumer polls its
// own 32 MFMA-fragment chunks (16B) with sc0+sc1 loads until all tags == t;
// values are then already in registers. Double buffer + every-WG-is-both-
// producer-and-consumer => no one runs >1 step ahead => no overwrite hazard.
//
// MFMA convention (swapped, layout-safe k-slot mapping k = ks*32 + lg*8 + j):
//   acc = MFMA(W_frag, act_frag, acc); D: row = 4*lg+reg = out-col offset,
//   col = l15 = batch row. Lane owns 4 adjacent h-cols of one batch row.

#define TT 512
#define FF 256
#define HH 512
#define G3 1536
#define NWG 256
#define NTHR 256   // 4 waves: 1 worker + 3 heaters

typedef __attribute__((ext_vector_type(8))) short short8;   // 8 x bf16
typedef __attribute__((ext_vector_type(4))) float f32x4;
typedef unsigned int u32;
typedef unsigned long long u64;

union U4 { uint4 v; u32 u[4]; u64 q[2]; };

__device__ __forceinline__ unsigned short f2bf(float f) {
  union { float f; unsigned u; } x; x.f = f;
  return (unsigned short)((x.u + 0x7fffu + ((x.u >> 16) & 1u)) >> 16);  // RNE
}

__device__ __forceinline__ unsigned pk2(float a, float b) {
  union { __hip_bfloat162 h; unsigned u; } x;
  x.h = __float22bfloat162_rn(make_float2(a, b));
  return x.u;  // low 16 = a, high 16 = b
}

__device__ __forceinline__ float sigm(float x) {
  return __builtin_amdgcn_rcpf(1.f + __expf(-x));
}

#define MFMA(a, b, c) __builtin_amdgcn_mfma_f32_16x16x32_bf16((a), (b), (c), 0, 0, 0)

__global__ __launch_bounds__(NTHR, 1) void gru_fused(
    const float* __restrict__ data,
    const float* __restrict__ Wi_f, const float* __restrict__ bi_f,
    const float* __restrict__ Wh_f, const float* __restrict__ bhn_f,
    const float* __restrict__ Wi_b, const float* __restrict__ bi_b,
    const float* __restrict__ Wh_b, const float* __restrict__ bhn_b,
    float* __restrict__ out,
    u32* __restrict__ hbuf)   // [unit][buf][row16][col512] tagged u32
{
  __shared__ int done;
  if (threadIdx.x == 0) done = 0;
  __syncthreads();

  if (threadIdx.x >= 64) {
    // ---- heater waves: register-only FMA spin, no memory traffic ----
    float a0 = (float)threadIdx.x, a1 = a0 + 1.f, a2 = a0 + 2.f, a3 = a0 + 3.f;
    while (true) {
#pragma unroll
      for (int i = 0; i < 256; ++i) {
        a0 = __builtin_fmaf(a0, 1.0000001f, 1e-9f);
        a1 = __builtin_fmaf(a1, 1.0000001f, 1e-9f);
        a2 = __builtin_fmaf(a2, 1.0000001f, 1e-9f);
        a3 = __builtin_fmaf(a3, 1.0000001f, 1e-9f);
      }
      if (*(volatile int*)&done) break;
    }
    asm volatile("" :: "v"(a0), "v"(a1), "v"(a2), "v"(a3));  // keep live
    return;
  }

  // ---- worker wave (identical to R4b) ----
  const int wg   = blockIdx.x;
  const int unit = wg & 7;
  const int s    = wg >> 3;     // column slice 0..31
  const int dir  = unit >> 2;
  const int bg   = unit & 3;
  const int lane = threadIdx.x; // 0..63
  const int l15  = lane & 15;
  const int lg   = lane >> 4;

  const float* Wi  = dir ? Wi_b  : Wi_f;
  const float* Wh  = dir ? Wh_b  : Wh_f;
  const float* bi  = dir ? bi_b  : bi_f;
  const float* bhn = dir ? bhn_b : bhn_f;

  const int colT = s * 16 + l15;        // weight-fragment column (A m-index)
  const int colBase = s * 16 + lg * 4;  // this lane's 4 output columns

  // ---- one-time: weight A-fragments into registers (k = ks*32+lg*8+j) ----
  short8 whf[3][16];
#pragma unroll
  for (int g = 0; g < 3; ++g)
#pragma unroll
    for (int ks = 0; ks < 16; ++ks) {
      short8 v;
#pragma unroll
      for (int j = 0; j < 8; ++j)
        v[j] = (short)f2bf(Wh[(size_t)(ks * 32 + lg * 8 + j) * G3 + g * HH + colT]);
      whf[g][ks] = v;
    }
  short8 wif[3][8];
#pragma unroll
  for (int g = 0; g < 3; ++g)
#pragma unroll
    for (int ks = 0; ks < 8; ++ks) {
      short8 v;
#pragma unroll
      for (int j = 0; j < 8; ++j)
        v[j] = (short)f2bf(Wi[(size_t)(ks * 32 + lg * 8 + j) * G3 + g * HH + colT]);
      wif[g][ks] = v;
    }
  float biR[4], biZ[4], biN[4], bhc[4];
#pragma unroll
  for (int j = 0; j < 4; ++j) {
    biR[j] = bi[colBase + j];
    biZ[j] = bi[HH + colBase + j];
    biN[j] = bi[2 * HH + colBase + j];
    bhc[j] = bhn[colBase + j];
  }

  const float* xbase = data + (size_t)(bg * 16 + l15) * TT * FF;
  float hp[4] = {0.f, 0.f, 0.f, 0.f};  // fp32 carry: batch l15, cols colBase+j

  for (int t = 0; t < TT; ++t) {
    // ---- xg phase (h-independent; issues before the poll) ----
    f32x4 accR = {0.f, 0.f, 0.f, 0.f};
    f32x4 accZ = {0.f, 0.f, 0.f, 0.f};
    f32x4 xN   = {0.f, 0.f, 0.f, 0.f};
    {
      const float* xr = xbase + (size_t)t * FF;
#pragma unroll
      for (int ks = 0; ks < 8; ++ks) {
        float4 x0 = *(const float4*)(xr + ks * 32 + lg * 8);
        float4 x1 = *(const float4*)(xr + ks * 32 + lg * 8 + 4);
        union { short8 s; unsigned u[4]; } a;
        a.u[0] = pk2(x0.x, x0.y); a.u[1] = pk2(x0.z, x0.w);
        a.u[2] = pk2(x1.x, x1.y); a.u[3] = pk2(x1.z, x1.w);
        accR = MFMA(wif[0][ks], a.s, accR);
        accZ = MFMA(wif[1][ks], a.s, accZ);
        xN   = MFMA(wif[2][ks], a.s, xN);
      }
    }

    // ---- tagged poll: reload own fragments until all 32 chunk-tags == t ----
    const u32 tag = (u32)t;
    const u32* hb = hbuf + ((size_t)(unit * 2 + (t & 1)) << 13);  // 16*512 u32
    U4 q[32];
    while (true) {
#pragma unroll
      for (int ks = 0; ks < 16; ++ks) {
        const u32* p = hb + l15 * 512 + ks * 32 + lg * 8;
        asm volatile("global_load_dwordx4 %0, %1, off sc0 sc1"
                     : "=v"(q[2 * ks].v) : "v"(p));
        asm volatile("global_load_dwordx4 %0, %1, off sc0 sc1"
                     : "=v"(q[2 * ks + 1].v) : "v"(p + 4));
      }
      asm volatile("s_waitcnt vmcnt(0)" ::: "memory");
      u32 bad = 0;
#pragma unroll
      for (int c = 0; c < 32; ++c) {
        bad |= (q[c].u[0] ^ tag) & 0xffffu;   // tag of 8B granule {w0,w1}
        bad |= (q[c].u[3] ^ tag) & 0xffffu;   // tag of 8B granule {w2,w3}
      }
      if (__all(bad == 0)) break;
    }

    // ---- pack B-fragments (strip tags) + hg MFMAs ----
    f32x4 hN = {0.f, 0.f, 0.f, 0.f};
#pragma unroll
    for (int ks = 0; ks < 16; ++ks) {
      union { short8 s; unsigned u[4]; } a;
#pragma unroll
      for (int i = 0; i < 2; ++i) {
        const U4& c = q[2 * ks + i];
        a.u[2 * i]     = __builtin_amdgcn_perm(c.u[1], c.u[0], 0x07060302u);
        a.u[2 * i + 1] = __builtin_amdgcn_perm(c.u[3], c.u[2], 0x07060302u);
      }
      accR = MFMA(whf[0][ks], a.s, accR);
      accZ = MFMA(whf[1][ks], a.s, accZ);
      hN   = MFMA(whf[2][ks], a.s, hN);
    }

    // ---- gates: lane holds (batch=l15, cols=colBase..+3) ----
    float hv[4];
#pragma unroll
    for (int j = 0; j < 4; ++j) {
      float r = sigm(accR[j] + biR[j]);
      float z = sigm(accZ[j] + biZ[j]);
      float e = __expf(2.f * (xN[j] + biN[j] + r * (hN[j] + bhc[j])));
      float n = 1.f - 2.f * __builtin_amdgcn_rcpf(e + 1.f);  // tanh
      hv[j] = (1.f - z) * n + z * hp[j];
      hp[j] = hv[j];
    }

    // ---- publish: two tagged 8B atomic stores, no drain, no flag ----
    {
      U4 w;
      const u32 wtag = (u32)(t + 1);
#pragma unroll
      for (int j = 0; j < 4; ++j)
        w.u[j] = ((u32)f2bf(hv[j]) << 16) | wtag;
      u32* ho = hbuf + ((size_t)(unit * 2 + ((t + 1) & 1)) << 13);
      u64* pdst = (u64*)(ho + l15 * 512 + s * 16 + lg * 4);
      __hip_atomic_store(&pdst[0], w.q[0], __ATOMIC_RELAXED, __HIP_MEMORY_SCOPE_AGENT);
      __hip_atomic_store(&pdst[1], w.q[1], __ATOMIC_RELAXED, __HIP_MEMORY_SCOPE_AGENT);
    }

    // ---- out store (off critical path): one float4 per lane ----
    *(float4*)(out + ((size_t)(bg * 16 + l15) * TT + t) * 1024 + (size_t)dir * HH + colBase)
        = make_float4(hv[0], hv[1], hv[2], hv[3]);
  }

  // release the heaters
  __hip_atomic_store(&done, 1, __ATOMIC_RELAXED, __HIP_MEMORY_SCOPE_WORKGROUP);
}

extern "C" void kernel_launch(void* const* d_in, const int* in_sizes, int n_in,
                              void* d_out, int out_size, void* d_ws, size_t ws_size,
                              hipStream_t stream) {
  const float* data  = (const float*)d_in[0];
  const float* Wi_f  = (const float*)d_in[1];
  const float* bi_f  = (const float*)d_in[2];
  const float* Wh_f  = (const float*)d_in[3];
  const float* bhn_f = (const float*)d_in[4];
  const float* Wi_b  = (const float*)d_in[5];
  const float* bi_b  = (const float*)d_in[6];
  const float* Wh_b  = (const float*)d_in[7];
  const float* bhn_b = (const float*)d_in[8];
  float* out = (float*)d_out;

  // ws: [0, 512KB) tagged h double buffers (8 units x 2 x 16 x 512 u32).
  // memset(0) == valid tag-0 zero state => uniform t=0 path.
  u32* hbuf = (u32*)d_ws;
  (void)hipMemsetAsync(d_ws, 0, 524288, stream);

  gru_fused<<<NWG, NTHR, 0, stream>>>(data, Wi_f, bi_f, Wh_f, bhn_f,
                                      Wi_b, bi_b, Wh_b, bhn_b, out, hbuf);
}